// Round 2
// baseline (549.490 us; speedup 1.0000x reference)
//
#include <hip/hip_runtime.h>

typedef __attribute__((ext_vector_type(8))) short short8;
typedef __attribute__((ext_vector_type(4))) short shortx4;
typedef __attribute__((ext_vector_type(4))) float floatx4;

#define QK_LD 136   // 128 + 8 pad (shorts): rows 16B-aligned, benign bank pattern
#define VT_LD 72    // 64 + 8 pad (shorts)

// fp32 -> bf16 round-to-nearest-even
__device__ __forceinline__ unsigned short f2bf(float f) {
  union { float f; unsigned int u; } v; v.f = f;
  unsigned int u = v.u;
  u += 0x7fffu + ((u >> 16) & 1u);
  return (unsigned short)(u >> 16);
}

__launch_bounds__(256, 3)
__global__ void attn_fwd(const float* __restrict__ qkv,
                         const int* __restrict__ kvlen_p,
                         float* __restrict__ out) {
  // 2*64*136*2 + 128*72*2 = 53248 B -> 3 blocks/CU (159744 <= 163840)
  __shared__ unsigned short Qs[64 * QK_LD];   // Q (bf16); wave-local P reuse after scores
  __shared__ unsigned short Ks[64 * QK_LD];
  __shared__ unsigned short Vts[128 * VT_LD]; // V^T [d][s], swizzled cols

  const int bid  = blockIdx.x;
  const int h    = bid & 31;
  const int b    = bid >> 5;
  const int tid  = threadIdx.x;
  const int lane = tid & 63;
  const int w    = tid >> 6;        // wave id: owns query rows 16w..16w+15
  const int l15  = lane & 15;
  const int quad = lane >> 4;
  const int kvlen = kvlen_p[0];

  const float4* g4 = (const float4*)qkv;  // row = 96 float4 (Q|K|V = 32|32|32)

  // ---------------- staging: global fp32 -> LDS bf16 ----------------
  #pragma unroll 2
  for (int it = 0; it < 8; ++it) {
    int i  = tid + 256 * it;          // 0..2047 : 64 rows x 32 float4-chunks
    int s  = i >> 5;
    int c4 = i & 31;
    int rb = ((b * 64 + s) * 32 + h) * 96;

    float4 dq = g4[rb + c4];
    shortx4 pq = { (short)f2bf(dq.x), (short)f2bf(dq.y), (short)f2bf(dq.z), (short)f2bf(dq.w) };
    *(shortx4*)&Qs[s * QK_LD + c4 * 4] = pq;

    float4 dk = g4[rb + 32 + c4];
    shortx4 pk = { (short)f2bf(dk.x), (short)f2bf(dk.y), (short)f2bf(dk.z), (short)f2bf(dk.w) };
    *(shortx4*)&Ks[s * QK_LD + c4 * 4] = pk;

    float4 dv = g4[rb + 64 + c4];
    // transpose-scatter V -> Vt[d][s]; col swizzle keeps stores ~2-way (free)
    // d = 4*c4 + j, j=0..3 -> (d>>3)&7 == (c4>>1)&7 for all 4 elements
    int col = (s + 8 * ((c4 >> 1) & 7)) & 63;
    unsigned short* vp = &Vts[(c4 * 4) * VT_LD + col];
    vp[0 * VT_LD] = f2bf(dv.x);
    vp[1 * VT_LD] = f2bf(dv.y);
    vp[2 * VT_LD] = f2bf(dv.z);
    vp[3 * VT_LD] = f2bf(dv.w);
  }
  __syncthreads();  // only barrier; afterwards each wave is independent

  // ---------------- scores: S = Q K^T * scale ----------------
  const float scale = 0.08838834764831845f;  // 1/sqrt(128)
  floatx4 zero4 = {0.f, 0.f, 0.f, 0.f};
  floatx4 accS[4] = {zero4, zero4, zero4, zero4};
  const int arow = (16 * w + l15) * QK_LD + 8 * quad;  // A-frag base (Q, later P)

  #pragma unroll
  for (int ks = 0; ks < 4; ++ks) {
    short8 a = *(const short8*)&Qs[arow + 32 * ks];
    #pragma unroll
    for (int nt = 0; nt < 4; ++nt) {
      short8 bf = *(const short8*)&Ks[(16 * nt + l15) * QK_LD + 32 * ks + 8 * quad];
      accS[nt] = __builtin_amdgcn_mfma_f32_16x16x32_bf16(a, bf, accS[nt], 0, 0, 0);
    }
  }

  // ---------------- softmax (C-layout: row = 4*quad + r, col = 16*nt + l15) ----------------
  float sv[4][4];
  #pragma unroll
  for (int nt = 0; nt < 4; ++nt) {
    bool masked = (16 * nt + l15) >= kvlen;
    #pragma unroll
    for (int r = 0; r < 4; ++r)
      sv[nt][r] = masked ? -__builtin_inff() : accS[nt][r] * scale;
  }
  float rowmax[4], rsum[4], rcpl[4];
  #pragma unroll
  for (int r = 0; r < 4; ++r)
    rowmax[r] = fmaxf(fmaxf(sv[0][r], sv[1][r]), fmaxf(sv[2][r], sv[3][r]));
  #pragma unroll
  for (int m = 1; m <= 8; m <<= 1) {
    #pragma unroll
    for (int r = 0; r < 4; ++r)
      rowmax[r] = fmaxf(rowmax[r], __shfl_xor(rowmax[r], m));
  }

  // write P (bf16) into this wave's dead Q rows — wave-local DS ops are in-order, no barrier
  unsigned short* Pbase = &Qs[16 * w * QK_LD];
  #pragma unroll
  for (int r = 0; r < 4; ++r) rsum[r] = 0.f;
  #pragma unroll
  for (int nt = 0; nt < 4; ++nt) {
    #pragma unroll
    for (int r = 0; r < 4; ++r) {
      float e = __expf(sv[nt][r] - rowmax[r]);
      rsum[r] += e;
      Pbase[(4 * quad + r) * QK_LD + 16 * nt + l15] = f2bf(e);
    }
  }
  #pragma unroll
  for (int m = 1; m <= 8; m <<= 1) {
    #pragma unroll
    for (int r = 0; r < 4; ++r)
      rsum[r] += __shfl_xor(rsum[r], m);
  }
  #pragma unroll
  for (int r = 0; r < 4; ++r) rcpl[r] = 1.0f / rsum[r];

  // ---------------- O = P V ----------------
  floatx4 accO[8] = {zero4, zero4, zero4, zero4, zero4, zero4, zero4, zero4};
  #pragma unroll
  for (int ks = 0; ks < 2; ++ks) {
    short8 a = *(const short8*)&Qs[arow + 32 * ks];  // P A-frag: row l15, k contiguous
    #pragma unroll
    for (int nt = 0; nt < 8; ++nt) {
      int vrow = 16 * nt + l15;                      // d
      int vcol = ((32 * ks + 8 * quad) + 8 * ((vrow >> 3) & 7)) & 63;  // swizzle-aware, mult of 8
      short8 bf = *(const short8*)&Vts[vrow * VT_LD + vcol];
      accO[nt] = __builtin_amdgcn_mfma_f32_16x16x32_bf16(a, bf, accO[nt], 0, 0, 0);
    }
  }

  // ---------------- epilogue: scale by 1/l, store fp32 ----------------
  // lane holds rows 16w+4*quad+r (same lanes own rcpl[r]), cols d = 16*nt+l15
  const int obase = ((b * 64 + 16 * w + 4 * quad) * 32 + h) * 128 + l15;
  #pragma unroll
  for (int nt = 0; nt < 8; ++nt) {
    #pragma unroll
    for (int r = 0; r < 4; ++r)
      out[obase + r * 4096 + nt * 16] = accO[nt][r] * rcpl[r];
  }
}

extern "C" void kernel_launch(void* const* d_in, const int* in_sizes, int n_in,
                              void* d_out, int out_size, void* d_ws, size_t ws_size,
                              hipStream_t stream) {
  const float* qkv = (const float*)d_in[0];
  const int* kvlen = (const int*)d_in[1];
  float* out       = (float*)d_out;
  attn_fwd<<<dim3(128 * 32), dim3(256), 0, stream>>>(qkv, kvlen, out);
}